// Round 3
// baseline (1905.442 us; speedup 1.0000x reference)
//
#include <hip/hip_runtime.h>
#include <stdint.h>

// BiLSTM-CRF forward on MI355X.
// R3: single-WG-per-(dir,group) LSTM with register-resident fp8 w_hh
//     (no cross-WG sync at all; 1 __syncthreads per step).
typedef unsigned short u16;
typedef __attribute__((ext_vector_type(4))) float f32x4;
typedef __attribute__((ext_vector_type(8))) short short8;

#define OFF_BIAS   ((size_t)0)           // 2048*4 combined b_ih+b_hh
#define OFF_WFRAG  ((size_t)8192)        // 2*8*2*4*8*64*8 = 512 KB fp8 frag-ordered w_hh
#define OFF_HHIST  ((size_t)1048576)     // [2][64][512][256] u16 = 32 MB
#define OFF_FEATS  ((size_t)34603008)    // 32768*9*4 = 1.13 MB
#define OFF_XG     ((size_t)37748736)    // [2*4][512][512 threads][32] u16 = 128 MB

__device__ __forceinline__ u16 f2bf(float f) {
  union { float f; uint32_t u; } v; v.f = f;
  uint32_t u = v.u;
  return (u16)((u + 0x7fffu + ((u >> 16) & 1u)) >> 16);
}
__device__ __forceinline__ float bf2f(u16 h) {
  union { uint32_t u; float f; } v; v.u = ((uint32_t)h) << 16; return v.f;
}
__device__ __forceinline__ short8 pack8(f32x4 a, f32x4 b) {
  short8 r;
  r[0] = (short)f2bf(a[0]); r[1] = (short)f2bf(a[1]);
  r[2] = (short)f2bf(a[2]); r[3] = (short)f2bf(a[3]);
  r[4] = (short)f2bf(b[0]); r[5] = (short)f2bf(b[1]);
  r[6] = (short)f2bf(b[2]); r[7] = (short)f2bf(b[3]);
  return r;
}

// ---- combined input-gate bias ----
__global__ void bias_kernel(const float* __restrict__ bihf, const float* __restrict__ bhhf,
                            const float* __restrict__ bihb, const float* __restrict__ bhhb,
                            float* __restrict__ bias) {
  int n = blockIdx.x * 256 + threadIdx.x;
  if (n < 1024) bias[n] = bihf[n] + bhhf[n];
  else          bias[n] = bihb[n - 1024] + bhhb[n - 1024];
}

// ---- w_hh -> fp8 e4m3 B-fragments (x16 scale), K-order permuted by pi ----
// pi(u): k = w*32 + n*2 + ubi  where u = w*32 + ubi*16 + n
// wfrag[(((((d*8+w)*2+ubi)*4+gate)*8+kt)*64+l)*8 + j] = fp8(16 * W[row][u_col(k)])
// row = gate*256 + w*32 + ubi*16 + (l&15); k = kt*32 + (l>>4)*8 + j
__global__ void wfrag_prep_kernel(const float* __restrict__ whhf,
                                  const float* __restrict__ whhb,
                                  uint8_t* __restrict__ wfrag) {
  int gid = blockIdx.x * 256 + threadIdx.x;   // 0..32767
  const int l    = gid & 63;
  const int kt   = (gid >> 6) & 7;
  const int gate = (gid >> 9) & 3;
  const int ubi  = (gid >> 11) & 1;
  const int w    = (gid >> 12) & 7;
  const int d    = (gid >> 15) & 1;
  const float* W = d ? whhb : whhf;
  const int n = l & 15, q = l >> 4;
  const int row = gate * 256 + w * 32 + ubi * 16 + n;
  uint32_t out[2] = {0u, 0u};
  #pragma unroll
  for (int jj = 0; jj < 4; ++jj) {
    const int k0 = kt * 32 + q * 8 + jj * 2;       // even
    const int k1 = k0 + 1;                          // odd
    const int u0 = (k0 >> 5) * 32 + (k0 & 1) * 16 + ((k0 & 31) >> 1);
    const int u1 = (k1 >> 5) * 32 + (k1 & 1) * 16 + ((k1 & 31) >> 1);
    const float f0 = W[(size_t)row * 256 + u0] * 16.0f;
    const float f1 = W[(size_t)row * 256 + u1] * 16.0f;
    const int pk = __builtin_amdgcn_cvt_pk_fp8_f32(f0, f1, 0, false);
    out[jj >> 1] |= (uint32_t)(pk & 0xffff) << (16 * (jj & 1));
  }
  *(uint2*)(wfrag + (size_t)gid * 8) = make_uint2(out[0], out[1]);
}

// ---- xg = gather(emb) @ w_ih^T + bias, written in lstm lane order ----
// (gate g pre-doubled so tanh uses exp(2y) form without a runtime mul)
__global__ void __launch_bounds__(256) xg_gemm_kernel(
    const int* __restrict__ sent, const float* __restrict__ emb,
    const float* __restrict__ w_ih_f, const float* __restrict__ w_ih_b,
    const float* __restrict__ bias, u16* __restrict__ xgf)
{
  extern __shared__ char smem[];
  u16*   Al    = (u16*)smem;             // [128][136]
  u16*   Bl    = (u16*)(smem + 34816);   // [128][136]
  float* biasl = (float*)(smem + 69632); // [128]
  int*   tokl  = (int*)(smem + 70144);   // [128]

  const int tid = threadIdx.x;
  const int m0 = blockIdx.y * 128;
  const int n0 = blockIdx.x * 128;
  const int d  = n0 >> 10;
  const int nr0 = n0 & 1023;
  const float* wih = d ? w_ih_b : w_ih_f;

  if (tid < 128) { tokl[tid] = sent[m0 + tid]; biasl[tid] = bias[n0 + tid]; }
  __syncthreads();

  f32x4 acc[4][4];
  #pragma unroll
  for (int i = 0; i < 4; ++i)
    #pragma unroll
    for (int j = 0; j < 4; ++j) acc[i][j] = (f32x4){0.f, 0.f, 0.f, 0.f};

  const int wv = tid >> 6, l = tid & 63;
  const int mh = (wv >> 1) * 64, nh = (wv & 1) * 64;
  const int fr = l & 15, fq = l >> 4;
  const int rr = tid >> 1, c0 = (tid & 1) * 64;

  for (int kc = 0; kc < 2; ++kc) {
    const int k0 = kc * 128;
    const float* asrc = emb + (size_t)tokl[rr] * 256 + k0 + c0;
    const float* bsrc = wih + (size_t)(nr0 + rr) * 256 + k0 + c0;
    u16* adst = Al + rr * 136 + c0;
    u16* bdst = Bl + rr * 136 + c0;
    #pragma unroll
    for (int gdx = 0; gdx < 8; ++gdx) {
      f32x4 a0 = *(const f32x4*)(asrc + gdx * 8);
      f32x4 a1 = *(const f32x4*)(asrc + gdx * 8 + 4);
      *(short8*)(adst + gdx * 8) = pack8(a0, a1);
      f32x4 b0 = *(const f32x4*)(bsrc + gdx * 8);
      f32x4 b1 = *(const f32x4*)(bsrc + gdx * 8 + 4);
      *(short8*)(bdst + gdx * 8) = pack8(b0, b1);
    }
    __syncthreads();
    #pragma unroll
    for (int ks = 0; ks < 4; ++ks) {
      short8 af[4], bfr[4];
      #pragma unroll
      for (int i = 0; i < 4; ++i)
        af[i] = *(const short8*)(Al + (mh + i * 16 + fr) * 136 + ks * 32 + fq * 8);
      #pragma unroll
      for (int j = 0; j < 4; ++j)
        bfr[j] = *(const short8*)(Bl + (nh + j * 16 + fr) * 136 + ks * 32 + fq * 8);
      #pragma unroll
      for (int i = 0; i < 4; ++i)
        #pragma unroll
        for (int j = 0; j < 4; ++j)
          acc[i][j] = __builtin_amdgcn_mfma_f32_16x16x32_bf16(af[i], bfr[j], acc[i][j], 0, 0, 0);
    }
    __syncthreads();
  }

  // epilogue -> xgf[((d*4+g)*512 + s)*16384 + lt*32 + ubi*16 + gate*4 + r]
  #pragma unroll
  for (int i = 0; i < 4; ++i)
    #pragma unroll
    for (int j = 0; j < 4; ++j)
      #pragma unroll
      for (int r2 = 0; r2 < 4; ++r2) {
        const int gm  = m0 + mh + i * 16 + fq * 4 + r2;
        const int gnl = nh + j * 16 + fr;
        const int grow = (n0 & 1023) + gnl;
        const int gate = grow >> 8, u = grow & 255;
        float v = acc[i][j][r2] + biasl[gnl];
        if (gate == 2) v *= 2.0f;
        const int bb = gm >> 9, ss = gm & 511;
        const int gg = bb >> 4, mloc = bb & 15;
        const int q2 = mloc >> 2, r3 = mloc & 3;
        const int w2 = u >> 5, ubi = (u >> 4) & 1, n2 = u & 15;
        const int lt = w2 * 64 + q2 * 16 + n2;
        const size_t idx = ((size_t)(d * 4 + gg) * 512 + ss) * 16384 + (size_t)lt * 32 + ubi * 16 + gate * 4 + r3;
        xgf[idx] = f2bf(v);
      }
}

// ---- self-contained BiLSTM recurrence: 8 WGs = dir(2) x batch-group(4 of 16) ----
// 512 threads = 8 waves; wave w owns units [32w,32w+32) x 4 gates, weights in VGPRs.
__global__ void __launch_bounds__(512, 2) lstm_kernel(
    const u16* __restrict__ xgf, const uint8_t* __restrict__ wfrag,
    u16* __restrict__ hhist)
{
  __shared__ uint8_t hx[2 * 16 * 264];   // fp8 h double-buffer, stride 264

  const int tid = threadIdx.x;
  const int bid = blockIdx.x;            // 0..7
  const int d = bid >> 2, g = bid & 3;
  const int w = tid >> 6, l = tid & 63;
  const int n = l & 15, q = l >> 4;

  // register-resident fp8 weight fragments: 128 VGPRs
  long long wreg[2][4][8];
  {
    const uint8_t* wb = wfrag + ((size_t)(d * 8 + w) * 2) * 4 * 8 * 64 * 8;
    #pragma unroll
    for (int ubi = 0; ubi < 2; ++ubi)
      #pragma unroll
      for (int gate = 0; gate < 4; ++gate)
        #pragma unroll
        for (int kt = 0; kt < 8; ++kt)
          wreg[ubi][gate][kt] =
            *(const long long*)(wb + ((((size_t)(ubi * 4 + gate) * 8) + kt) * 64 + l) * 8);
  }

  for (int i = tid; i < 2112; i += 512) ((uint32_t*)hx)[i] = 0u;  // h_{-1} = 0

  const u16* xslice = xgf + (size_t)(d * 4 + g) * 512 * 16384;
  float cst[2][4] = {};
  u16* hhb = hhist + ((size_t)(d * 64 + g * 16) * 512) * 256 + (w * 32 + n);

  // prefetch xg for t=0
  uint4 xc[4];
  {
    const uint4* p = (const uint4*)(xslice + (size_t)(d ? 511 : 0) * 16384 + tid * 32);
    xc[0] = p[0]; xc[1] = p[1]; xc[2] = p[2]; xc[3] = p[3];
  }
  __syncthreads();

  const float S1 = 1.0f / 256.0f;   // unscale fp8 (16*16); gate g acc additionally x2
  const float S2 = 2.0f / 256.0f;

  for (int t = 0; t < 512; ++t) {
    const int t_eff = d ? (511 - t) : t;
    const int cb = t & 1, nb = cb ^ 1;

    // A fragments from hx[cb]: lane -> m = l&15, k = kt*32 + q*8 + j
    long long afr[8];
    const uint8_t* hr = hx + cb * 4224 + (l & 15) * 264 + q * 8;
    #pragma unroll
    for (int kt = 0; kt < 8; ++kt)
      afr[kt] = *(const long long*)(hr + kt * 32);

    // MFMA: 2 unit-blocks x 4 gates x 8 K-chunks
    f32x4 acc[2][4];
    #pragma unroll
    for (int ubi = 0; ubi < 2; ++ubi)
      #pragma unroll
      for (int gate = 0; gate < 4; ++gate) {
        f32x4 a = {0.f, 0.f, 0.f, 0.f};
        #pragma unroll
        for (int kt = 0; kt < 8; ++kt)
          a = __builtin_amdgcn_mfma_f32_16x16x32_fp8_fp8(afr[kt], wreg[ubi][gate][kt], a, 0, 0, 0);
        acc[ubi][gate] = a;
      }

    // gate math; lane holds batches m=q*4+r, units u = w*32 + ubi*16 + n
    const u16* xcu = (const u16*)xc;
    float hsc[2][4];
    u16* hhs = hhb + (size_t)t_eff * 256;
    #pragma unroll
    for (int ubi = 0; ubi < 2; ++ubi) {
      #pragma unroll
      for (int r = 0; r < 4; ++r) {
        const float iv = fmaf(acc[ubi][0][r], S1, bf2f(xcu[ubi * 16 + 0 + r]));
        const float fv = fmaf(acc[ubi][1][r], S1, bf2f(xcu[ubi * 16 + 4 + r]));
        const float gv = fmaf(acc[ubi][2][r], S2, bf2f(xcu[ubi * 16 + 8 + r]));   // pre-doubled
        const float ov = fmaf(acc[ubi][3][r], S1, bf2f(xcu[ubi * 16 + 12 + r]));
        const float si = __builtin_amdgcn_rcpf(1.0f + __expf(-iv));
        const float sf = __builtin_amdgcn_rcpf(1.0f + __expf(-fv));
        const float so = __builtin_amdgcn_rcpf(1.0f + __expf(-ov));
        const float tg = 1.0f - 2.0f * __builtin_amdgcn_rcpf(1.0f + __expf(gv));
        const float c  = sf * cst[ubi][r] + si * tg;
        cst[ubi][r] = c;
        const float th = 1.0f - 2.0f * __builtin_amdgcn_rcpf(1.0f + __expf(2.0f * c));
        const float hv = so * th;
        hsc[ubi][r] = hv * 16.0f;
        hhs[(size_t)(q * 4 + r) * 512 * 256 + ubi * 16] = f2bf(hv);  // fire-and-forget
      }
    }

    // reload xc for t+1 (latency hidden across the barrier into next MFMA phase)
    {
      const int tn = (t < 511) ? (t + 1) : 511;
      const int sn = d ? (511 - tn) : tn;
      const uint4* p = (const uint4*)(xslice + (size_t)sn * 16384 + tid * 32);
      xc[0] = p[0]; xc[1] = p[1]; xc[2] = p[2]; xc[3] = p[3];
    }

    // publish h as fp8 pairs into hx[nb] at pi-order: byte k = w*32 + 2n + ubi
    {
      uint8_t* hw = hx + nb * 4224 + w * 32 + 2 * n;
      #pragma unroll
      for (int r = 0; r < 4; ++r) {
        const int pk = __builtin_amdgcn_cvt_pk_fp8_f32(hsc[0][r], hsc[1][r], 0, false);
        *(u16*)(hw + (q * 4 + r) * 264) = (u16)(pk & 0xffff);
      }
    }
    __syncthreads();
  }
}

// ---- feats = [hf|hb] @ w_out^T + b_out ----
__global__ void __launch_bounds__(256) proj_kernel(
    const u16* __restrict__ hhist, const float* __restrict__ w_out,
    const float* __restrict__ b_out, float* __restrict__ feats)
{
  __shared__ float wsm[9 * 512];
  __shared__ float bsm[9];
  const int tid = threadIdx.x;
  for (int i = tid; i < 4608; i += 256) wsm[i] = w_out[i];
  if (tid < 9) bsm[tid] = b_out[tid];
  __syncthreads();

  const int wv = tid >> 6, l = tid & 63;
  const int gw = blockIdx.x * 4 + wv;
  const int jb = l * 8;
  const int dd = jb >> 8;
  const int jloc = jb & 255;

  for (int qq = 0; qq < 8; ++qq) {
    const int pos = gw * 8 + qq;
    const int b = pos >> 9, s = pos & 511;
    const u16* hp = hhist + ((size_t)(dd * 64 + b) * 512 + s) * 256 + jloc;
    short8 hv8 = *(const short8*)hp;
    float hf[8];
    #pragma unroll
    for (int j = 0; j < 8; ++j) hf[j] = bf2f((u16)hv8[j]);
    float pt[9];
    #pragma unroll
    for (int tg2 = 0; tg2 < 9; ++tg2) {
      const float* wr = wsm + tg2 * 512 + jb;
      float a = 0.f;
      #pragma unroll
      for (int j = 0; j < 8; ++j) a = fmaf(hf[j], wr[j], a);
      pt[tg2] = a;
    }
    #pragma unroll
    for (int tg2 = 0; tg2 < 9; ++tg2)
      #pragma unroll
      for (int off = 32; off; off >>= 1)
        pt[tg2] += __shfl_xor(pt[tg2], off, 64);
    if (l == 0) {
      float* fo = feats + (size_t)pos * 9;
      #pragma unroll
      for (int tg2 = 0; tg2 < 9; ++tg2) fo[tg2] = pt[tg2] + bsm[tg2];
    }
  }
}

// ---- CRF NLL ----
__global__ void __launch_bounds__(64) crf_kernel(
    const float* __restrict__ feats, const int* __restrict__ tags,
    const float* __restrict__ strans, const float* __restrict__ etrans,
    const float* __restrict__ trans, float* out)
{
  __shared__ float em[512 * 9];
  __shared__ float tr[81];
  __shared__ int   tg[512];
  const int b = blockIdx.x, l = threadIdx.x;
  const float* fb = feats + (size_t)b * 512 * 9;
  for (int i = l; i < 4608; i += 64) em[i] = fb[i];
  for (int i = l; i < 512; i += 64) tg[i] = tags[b * 512 + i];
  if (l < 81) tr[l] = trans[l];
  __syncthreads();

  float sc = 0.f;
  for (int s = 1 + l; s < 512; s += 64)
    sc += tr[tg[s - 1] * 9 + tg[s]] + em[s * 9 + tg[s]];
  #pragma unroll
  for (int off = 32; off; off >>= 1) sc += __shfl_xor(sc, off, 64);
  const float score = sc + strans[tg[0]] + em[tg[0]] + etrans[tg[511]];

  const int jj = (l < 9) ? l : 0;
  float al = (l < 9) ? (strans[l] + em[l]) : -1e30f;
  for (int t = 1; t < 512; ++t) {
    float ai[9];
    #pragma unroll
    for (int i = 0; i < 9; ++i) ai[i] = __shfl(al, i, 64);
    float m = ai[0];
    #pragma unroll
    for (int i = 1; i < 9; ++i) m = fmaxf(m, ai[i]);
    float ssum = 0.f;
    #pragma unroll
    for (int i = 0; i < 9; ++i) ssum += __expf(ai[i] + tr[i * 9 + jj] - m);
    al = em[t * 9 + jj] + m + __logf(ssum);
  }
  float v = (l < 9) ? (al + etrans[l]) : -3.0e38f;
  float m2 = v;
  #pragma unroll
  for (int off = 32; off; off >>= 1) m2 = fmaxf(m2, __shfl_xor(m2, off, 64));
  float ex = (l < 9) ? __expf(v - m2) : 0.f;
  #pragma unroll
  for (int off = 32; off; off >>= 1) ex += __shfl_xor(ex, off, 64);
  const float logZ = m2 + __logf(ex);
  if (l == 0) atomicAdd(out, -(score - logZ) * (1.0f / 64.0f));
}

extern "C" void kernel_launch(void* const* d_in, const int* in_sizes, int n_in,
                              void* d_out, int out_size, void* d_ws, size_t ws_size,
                              hipStream_t stream) {
  (void)in_sizes; (void)n_in; (void)out_size; (void)ws_size;
  const int*   sent = (const int*)d_in[0];
  const int*   tags = (const int*)d_in[1];
  const float* emb  = (const float*)d_in[3];
  const float* wihf = (const float*)d_in[4];
  const float* whhf = (const float*)d_in[5];
  const float* bihf = (const float*)d_in[6];
  const float* bhhf = (const float*)d_in[7];
  const float* wihb = (const float*)d_in[8];
  const float* whhb = (const float*)d_in[9];
  const float* bihb = (const float*)d_in[10];
  const float* bhhb = (const float*)d_in[11];
  const float* wout = (const float*)d_in[12];
  const float* bout = (const float*)d_in[13];
  const float* strn = (const float*)d_in[14];
  const float* etrn = (const float*)d_in[15];
  const float* trn  = (const float*)d_in[16];

  char* ws = (char*)d_ws;
  float*   biasb = (float*)(ws + OFF_BIAS);
  uint8_t* wfrag = (uint8_t*)(ws + OFF_WFRAG);
  u16*     hhist = (u16*)(ws + OFF_HHIST);
  float*   feats = (float*)(ws + OFF_FEATS);
  u16*     xgf   = (u16*)(ws + OFF_XG);
  float*   out   = (float*)d_out;

  hipMemsetAsync(d_out, 0, sizeof(float), stream);

  hipFuncSetAttribute(reinterpret_cast<const void*>(xg_gemm_kernel),
                      hipFuncAttributeMaxDynamicSharedMemorySize, 70656);

  bias_kernel<<<8, 256, 0, stream>>>(bihf, bhhf, bihb, bhhb, biasb);
  wfrag_prep_kernel<<<128, 256, 0, stream>>>(whhf, whhb, wfrag);
  xg_gemm_kernel<<<dim3(16, 256), 256, 70656, stream>>>(sent, emb, wihf, wihb, biasb, xgf);
  lstm_kernel<<<8, 512, 0, stream>>>(xgf, wfrag, hhist);
  proj_kernel<<<1024, 256, 0, stream>>>(hhist, wout, bout, feats);
  crf_kernel<<<64, 64, 0, stream>>>(feats, tags, strn, etrn, trn, out);
}